// Round 10
// baseline (144.086 us; speedup 1.0000x reference)
//
#include <hip/hip_runtime.h>
#include <cstdint>
#include <cstddef>

#define DEVINL __device__ __forceinline__

constexpr int S_ = 2048;
constexpr int D_ = 512;
constexpr int H_ = 8;
constexpr float SCALE_ = 0.125f;                 // 1/sqrt(64)
constexpr float SCALE_L2E_ = 0.18033688011112f;  // SCALE * log2(e), for exp2-domain scores

using short8 = __attribute__((ext_vector_type(8))) short;
using f32x4  = __attribute__((ext_vector_type(4))) float;

DEVINL unsigned short f2bf(float f){
  unsigned u = __builtin_bit_cast(unsigned, f);
  u += 0x7FFFu + ((u >> 16) & 1u);          // round-to-nearest-even
  return (unsigned short)(u >> 16);
}
DEVINL float bf2f(unsigned short h){
  return __builtin_bit_cast(float, ((unsigned)h) << 16);
}

// Raw v_exp_f32 via the intrinsic (NOT inline asm: the TRANS-op result
// hazard needs compiler-inserted wait states; asm blobs are opaque to the
// hazard recognizer and produced NaNs in R5).
DEVINL float fast_exp2(float x){ return __builtin_amdgcn_exp2f(x); }

DEVINL void gload16(const void* g, void* l){
  __builtin_amdgcn_global_load_lds(
      (__attribute__((address_space(1))) void*)(g),
      (__attribute__((address_space(3))) void*)(l), 16, 0, 0);
}

// ---------------- cast f32 -> bf16, 8 elems/thread (x and Wv) ---------
__global__ void cast_x_kernel(const float* __restrict__ x, unsigned short* __restrict__ xb){
  int i = blockIdx.x * 256 + threadIdx.x;
  const float* p = x + (size_t)i * 8;
  float4 a = *(const float4*)p;
  float4 b = *(const float4*)(p + 4);
  short8 o;
  o[0]=f2bf(a.x); o[1]=f2bf(a.y); o[2]=f2bf(a.z); o[3]=f2bf(a.w);
  o[4]=f2bf(b.x); o[5]=f2bf(b.y); o[6]=f2bf(b.z); o[7]=f2bf(b.w);
  *(short8*)(xb + (size_t)i*8) = o;
}

// ---------------- mask (67MB int32) -> bit array (2MB) ----------------
__global__ void mask_bits_kernel(const int* __restrict__ mask, unsigned char* __restrict__ bits){
  unsigned tid = blockIdx.x * 256 + threadIdx.x;   // 2048 blocks -> 524288 threads
  #pragma unroll
  for (int it = 0; it < 4; ++it){
    size_t bidx = (size_t)tid + (size_t)it * 524288;
    const int* p = mask + bidx * 8;
    int4 a = *(const int4*)p;
    int4 c = *(const int4*)(p + 4);
    unsigned v = (unsigned)(a.x != 0)       | ((unsigned)(a.y != 0) << 1)
               | ((unsigned)(a.z != 0) << 2) | ((unsigned)(a.w != 0) << 3)
               | ((unsigned)(c.x != 0) << 4) | ((unsigned)(c.y != 0) << 5)
               | ((unsigned)(c.z != 0) << 6) | ((unsigned)(c.w != 0) << 7);
    bits[bidx] = (unsigned char)v;
  }
}

// ---------------- transpose+cast W [K][N] f32 -> WT [N][K] bf16 -------
// z: 0=Wq (SCALE*log2e folded), 1=Wk, 2=Wo.
__global__ void castT_kernel(const float* __restrict__ W0, const float* __restrict__ W1,
                             const float* __restrict__ W2, unsigned short* __restrict__ WT){
  __shared__ float tile[32][33];
  const int z = blockIdx.z;
  const float* W = (z==0) ? W0 : (z==1 ? W1 : W2);
  const float scale = (z==0) ? SCALE_L2E_ : 1.0f;
  unsigned short* out = WT + (size_t)z * D_ * D_;
  int n0 = blockIdx.x*32, k0 = blockIdx.y*32;
  int tx = threadIdx.x, ty = threadIdx.y;       // block (32,8)
  #pragma unroll
  for (int j=0;j<4;j++)
    tile[ty+j*8][tx] = W[(size_t)(k0+ty+j*8)*D_ + n0+tx];
  __syncthreads();
  #pragma unroll
  for (int j=0;j<4;j++)
    out[(size_t)(n0+ty+j*8)*D_ + k0+tx] = f2bf(tile[tx][ty+j*8]*scale);
}

// ---------------- GEMM: C[z] = A[z][M,512] @ BT[z][512,512]^T + bias --
// 128x128 tile, BK=64, 4 waves (2x2), mfma 16x16x32 bf16.
// LDS XOR-swizzled via pre-swizzled global_load_lds source (rule #21).
template<typename OutT>
__global__ __launch_bounds__(256) void gemm_bt(
    const unsigned short* __restrict__ A, long long Az,
    const unsigned short* __restrict__ BT, long long Bz,
    const float* __restrict__ bias0, const float* __restrict__ bias1,
    const float* __restrict__ bias2, const float* __restrict__ bias3,
    float bs0, float bs1, float bs2, float bs3,
    OutT* __restrict__ Cp, long long Cz)
{
  __shared__ unsigned short As[128*64];
  __shared__ unsigned short Bs[128*64];
  const int z = blockIdx.z;
  const unsigned short* Ab = A + (size_t)z*Az;
  const unsigned short* Bb = BT + (size_t)z*Bz;
  const float* bias = (z==0) ? bias0 : (z==1 ? bias1 : (z==2 ? bias2 : bias3));
  const float bscale = (z==0) ? bs0 : (z==1 ? bs1 : (z==2 ? bs2 : bs3));
  OutT* C = Cp + (size_t)z*Cz;
  const int m0 = blockIdx.y*128, n0 = blockIdx.x*128;
  const int t = threadIdx.x, lane = t & 63, w = t >> 6;
  const int wr = w >> 1, wc = w & 1;
  const int g = lane >> 4, lq = lane & 15;
  f32x4 acc[4][4] = {};
  for (int kk = 0; kk < D_; kk += 64){
    #pragma unroll
    for (int p = 0; p < 4; p++){
      int o = p*4096 + t*16;
      int row = o >> 7;                 // LDS row (0..127), 128B/row
      int cb  = o & 127;
      int scb = cb ^ ((row & 7) << 4);  // pre-swizzle the SOURCE
      gload16((const char*)Ab + ((size_t)(m0+row)*D_ + kk)*2 + scb, (char*)As + o);
      gload16((const char*)Bb + ((size_t)(n0+row)*D_ + kk)*2 + scb, (char*)Bs + o);
    }
    __syncthreads();
    #pragma unroll
    for (int ks = 0; ks < 2; ks++){
      short8 af[4], bf[4];
      #pragma unroll
      for (int i = 0; i < 4; i++){
        int rowA = wr*64 + i*16 + lq;
        af[i] = *(const short8*)((const char*)As + ((rowA*128 + ks*64 + g*16) ^ ((rowA&7)<<4)));
        int rowB = wc*64 + i*16 + lq;
        bf[i] = *(const short8*)((const char*)Bs + ((rowB*128 + ks*64 + g*16) ^ ((rowB&7)<<4)));
      }
      #pragma unroll
      for (int i = 0; i < 4; i++)
        #pragma unroll
        for (int j = 0; j < 4; j++)
          acc[i][j] = __builtin_amdgcn_mfma_f32_16x16x32_bf16(af[i], bf[j], acc[i][j], 0, 0, 0);
    }
    __syncthreads();
  }
  #pragma unroll
  for (int i = 0; i < 4; i++){
    #pragma unroll
    for (int j = 0; j < 4; j++){
      int col = n0 + wc*64 + j*16 + lq;
      float bvv = bias[col]*bscale;
      #pragma unroll
      for (int r = 0; r < 4; r++){
        int row = m0 + wr*64 + i*16 + g*4 + r;   // C/D: col=lane&15, row=4g+reg (m89)
        float v = acc[i][j][r] + bvv;
        if constexpr (sizeof(OutT) == 4) C[(size_t)row*D_ + col] = (OutT)v;
        else                             C[(size_t)row*D_ + col] = (OutT)f2bf(v);
      }
    }
  }
}

// ---------------- attention partial Z/M per q-row ---------------------
// Grid (8 qt of 256 rows, 8 kz, 32 bh); block = 4 waves of the SAME
// (b,h). 32KB K-tile staged once into LDS (pre-swizzled source, rule
// #21), one barrier, then register-only loop. Z/M accumulated as f32x4
// (v_pk_add/pk_fma; R7's spill was the Ab ring, not the vector accums).
__global__ __launch_bounds__(256) void attn_zm_kernel(
    const unsigned short* __restrict__ Q, const unsigned short* __restrict__ Kg,
    const unsigned* __restrict__ bitsW, float* __restrict__ Zb, float* __restrict__ Mb)
{
  __shared__ unsigned short Ks[256*64];   // 32KB, swizzled rows of 128B
  const int qt = blockIdx.x, kz = blockIdx.y, zz = blockIdx.z;
  const int b = zz >> 3, h = zz & 7;
  const int t = threadIdx.x, lane = t & 63, w = t >> 6;
  const int g = lane >> 4, lq = lane & 15;
  const int qbase = qt*256 + w*64;

  // stage K-tile: 8 x gload16 per thread, source pre-swizzled (rule #21)
  const char* Kgb = (const char*)Kg + ((size_t)(b*S_ + kz*256))*1024 + h*128;
  #pragma unroll
  for (int p = 0; p < 8; p++){
    int o = p*4096 + t*16;
    int row = o >> 7;                   // 128B per k-row
    int cb  = o & 127;
    int scb = cb ^ ((row & 7) << 4);
    gload16(Kgb + (size_t)row*1024 + scb, (char*)Ks + o);
  }

  // mask-bit words: 4 q-rows x 8 k-tiles, preloaded (static idx)
  unsigned wb[4][8];
  #pragma unroll
  for (int qs = 0; qs < 4; qs++){
    const uint4* wp = (const uint4*)(bitsW + ((size_t)(b*S_ + qbase + qs*16 + lq))*(S_/32) + kz*8);
    uint4 wA = wp[0], wB = wp[1];
    wb[qs][0]=wA.x; wb[qs][1]=wA.y; wb[qs][2]=wA.z; wb[qs][3]=wA.w;
    wb[qs][4]=wB.x; wb[qs][5]=wB.y; wb[qs][6]=wB.z; wb[qs][7]=wB.w;
  }

  short8 qf[4][2];                        // Q rows in regs (pre-scaled by SCALE*log2e)
  #pragma unroll
  for (int qs = 0; qs < 4; qs++)
    #pragma unroll
    for (int c = 0; c < 2; c++)
      qf[qs][c] = *(const short8*)(Q + ((size_t)(b*S_ + qbase + qs*16 + lq))*D_ + h*64 + c*32 + g*8);

  f32x4 Z4[4], M4[4];
  #pragma unroll
  for (int qs = 0; qs < 4; qs++){
    Z4[qs] = (f32x4){0.f,0.f,0.f,0.f};
    M4[qs] = (f32x4){0.f,0.f,0.f,0.f};
  }

  __syncthreads();                        // K-tile ready (the only barrier)

  #pragma unroll
  for (int i = 0; i < 16; ++i){           // i covers k rows i*16 .. i*16+15
    const int kt2 = i >> 1, ks = i & 1;
    const int row = i*16 + lq;
    const int sw = (row & 7) << 4;
    short8 A0 = *(const short8*)((const char*)Ks + row*128 + ((g*16) ^ sw));
    short8 A1 = *(const short8*)((const char*)Ks + row*128 + ((64 + g*16) ^ sw));
    #pragma unroll
    for (int qs = 0; qs < 4; qs++){
      f32x4 d = {0.f,0.f,0.f,0.f};
      d = __builtin_amdgcn_mfma_f32_16x16x32_bf16(A0, qf[qs][0], d, 0, 0, 0);
      d = __builtin_amdgcn_mfma_f32_16x16x32_bf16(A1, qf[qs][1], d, 0, 0, 0);
      // d[r]: score(exp2-dom) for kpos = kz*256 + i*16 + 4g + r,
      // q-row = qbase + qs*16 + lq (col=lane&15)
      unsigned nib = wb[qs][kt2] >> (ks*16 + g*4);
      f32x4 p, mf;
      #pragma unroll
      for (int r = 0; r < 4; r++){
        p[r]  = fast_exp2(d[r]);
        mf[r] = (float)((nib >> r) & 1u);
      }
      Z4[qs] += p;                        // v_pk_add_f32 x2
      M4[qs] += mf * p;                   // v_pk_fma_f32 x2 (contracted)
    }
  }
  // horizontal + merge 4 k-subsets (lane groups); one atomic per q-row
  #pragma unroll
  for (int qs = 0; qs < 4; qs++){
    float z = (Z4[qs][0] + Z4[qs][1]) + (Z4[qs][2] + Z4[qs][3]);
    float m = (M4[qs][0] + M4[qs][1]) + (M4[qs][2] + M4[qs][3]);
    z += __shfl_xor(z, 16);  m += __shfl_xor(m, 16);
    z += __shfl_xor(z, 32);  m += __shfl_xor(m, 32);
    if (g == 0){
      int base = (b*H_ + h)*S_ + qbase + qs*16 + lq;
      atomicAdd(&Zb[base], z);
      atomicAdd(&Mb[base], m);
    }
  }
}

// ---------------- finalize: s[b,h] = sum_q (Z-M)/Z --------------------
__global__ __launch_bounds__(256) void finalize_s(const float* __restrict__ Zb,
                                                  const float* __restrict__ Mb,
                                                  float* __restrict__ sbh){
  const int bh = blockIdx.x;            // 32 blocks
  const int t = threadIdx.x;
  const float* Z = Zb + (size_t)bh*S_;
  const float* M = Mb + (size_t)bh*S_;
  float acc = 0.f;
  #pragma unroll
  for (int q = t; q < S_; q += 256){
    float z = Z[q];
    acc += (z - M[q]) / z;
  }
  #pragma unroll
  for (int m = 1; m < 64; m <<= 1) acc += __shfl_xor(acc, m);
  __shared__ float wsum[4];
  if ((t & 63) == 0) wsum[t >> 6] = acc;
  __syncthreads();
  if (t == 0) sbh[bh] = wsum[0] + wsum[1] + wsum[2] + wsum[3];
}

// ---------------- fold s into Wo columns: WoST[b][n][k] = WoT[n][k]*s[b,k/64]
__global__ void scale_woT_kernel(const unsigned short* __restrict__ WoT,
                                 const float* __restrict__ sbh,
                                 unsigned short* __restrict__ outw){
  int i = blockIdx.x*256 + threadIdx.x;   // 131072 threads, 8 elems each
  size_t e = (size_t)i * 8;
  int k = (int)(e & 511);
  int n = (int)((e >> 9) & 511);
  int b = (int)(e >> 18);
  float sv = sbh[b*H_ + (k >> 6)];
  short8 wv = *(const short8*)(WoT + (size_t)n*D_ + k);
  short8 o;
  #pragma unroll
  for (int j = 0; j < 8; j++) o[j] = (short)f2bf(bf2f((unsigned short)wv[j]) * sv);
  *(short8*)(outw + e) = o;
}

// ---------------- bo2[b][n] = bo[n] + sum_c woST[b][n][c]*bv[c] -------
__global__ __launch_bounds__(256) void bo2_kernel(const unsigned short* __restrict__ woST,
                                                  const float* __restrict__ bv,
                                                  const float* __restrict__ bo,
                                                  float* __restrict__ bo2){
  const int b = blockIdx.x >> 1;          // 8 blocks x 256 threads
  const int n = (blockIdx.x & 1)*256 + threadIdx.x;
  const unsigned short* row = woST + ((size_t)b*D_ + n)*D_;
  float acc = 0.f;
  #pragma unroll
  for (int c = 0; c < D_; c += 8){
    short8 w8 = *(const short8*)(row + c);
    float4 b0 = *(const float4*)(bv + c);
    float4 b1 = *(const float4*)(bv + c + 4);
    acc += bf2f((unsigned short)w8[0])*b0.x + bf2f((unsigned short)w8[1])*b0.y
         + bf2f((unsigned short)w8[2])*b0.z + bf2f((unsigned short)w8[3])*b0.w
         + bf2f((unsigned short)w8[4])*b1.x + bf2f((unsigned short)w8[5])*b1.y
         + bf2f((unsigned short)w8[6])*b1.z + bf2f((unsigned short)w8[7])*b1.w;
  }
  bo2[b*D_ + n] = bo[n] + acc;
}

extern "C" void kernel_launch(void* const* d_in, const int* in_sizes, int n_in,
                              void* d_out, int out_size, void* d_ws, size_t ws_size,
                              hipStream_t stream) {
  (void)in_sizes; (void)n_in; (void)out_size; (void)ws_size;
  const float* x  = (const float*)d_in[0];
  const int* mask = (const int*)d_in[1];
  const float* Wq = (const float*)d_in[2];
  const float* bq = (const float*)d_in[3];
  const float* Wk = (const float*)d_in[4];
  const float* bk = (const float*)d_in[5];
  const float* Wv = (const float*)d_in[6];
  const float* bv = (const float*)d_in[7];
  const float* Wo = (const float*)d_in[8];
  const float* bo = (const float*)d_in[9];
  float* out = (float*)d_out;

  char* ws = (char*)d_ws;
  unsigned short* xb   = (unsigned short*)(ws);             // 8 MB, live to the end
  unsigned short* wT   = (unsigned short*)(ws +  8388608);  // WqT,WkT,WoT (3x512 KB)
  unsigned short* woT  = (unsigned short*)(ws +  8388608 + 2*524288);
  unsigned short* Qb   = (unsigned short*)(ws + 10485760);
  unsigned short* Kb   = (unsigned short*)(ws + 18874368);
  // old Vb region reused: Z/M partials + Wvb + W2T
  float*          Zbuf = (float*)(ws + 27262976);           // 256 KB
  float*          Mbuf = (float*)(ws + 27525120);           // 256 KB
  unsigned short* Wvb  = (unsigned short*)(ws + 27787264);  // 512 KB (Wv bf16, row-major)
  unsigned short* W2T  = (unsigned short*)(ws + 28311552);  // 4x512 KB
  unsigned short* woST = (unsigned short*)(ws + 35651584);  // 4x512 KB
  float*          sbh  = (float*)         (ws + 37748736);  // 32 floats
  float*          bo2  = (float*)         (ws + 37748864);  // 2048 floats
  // mask bit array (2MB) overlaps woST: bits die before scale_woT writes it
  unsigned char*  bits = (unsigned char*)(ws + 35651584);

  cast_x_kernel<<<2048, 256, 0, stream>>>(x, xb);
  cast_x_kernel<<<128, 256, 0, stream>>>(Wv, Wvb);
  castT_kernel<<<dim3(16,16,3), dim3(32,8), 0, stream>>>(Wq, Wk, Wo, wT);
  mask_bits_kernel<<<2048, 256, 0, stream>>>(mask, bits);

  // Q,K projections (V eliminated algebraically): z=0->Q, z=1->K
  gemm_bt<unsigned short><<<dim3(4,64,2), 256, 0, stream>>>(
      xb, 0LL, wT, 262144LL, bq, bk, bk, bk, SCALE_L2E_, 1.0f, 0.f, 0.f, Qb, 4194304LL);

  hipMemsetAsync(Zbuf, 0, 524288, stream);

  attn_zm_kernel<<<dim3(8,8,32), 256, 0, stream>>>(Qb, Kb, (const unsigned*)bits, Zbuf, Mbuf);
  finalize_s<<<32, 256, 0, stream>>>(Zbuf, Mbuf, sbh);

  scale_woT_kernel<<<512, 256, 0, stream>>>(woT, sbh, woST);

  // W2T[b][n][k] = sum_c woST[b][n][c] * Wv[k][c]  (bf16 out, no bias)
  gemm_bt<unsigned short><<<dim3(4,4,4), 256, 0, stream>>>(
      woST, 262144LL, Wvb, 0LL, bo, bo, bo, bo, 0.f, 0.f, 0.f, 0.f, W2T, 262144LL);

  bo2_kernel<<<8, 256, 0, stream>>>(woST, bv, bo, bo2);

  // out[b] = x[b] @ W2T[b]^T + bo2[b]  (fp32 out)
  gemm_bt<float><<<dim3(4,16,4), 256, 0, stream>>>(
      xb, 1048576LL, W2T, 262144LL, bo2, bo2+512, bo2+1024, bo2+1536,
      1.f, 1.f, 1.f, 1.f, out, 1048576LL);
}

// Round 11
// 128.632 us; speedup vs baseline: 1.1201x; 1.1201x over previous
//
#include <hip/hip_runtime.h>
#include <cstdint>
#include <cstddef>

#define DEVINL __device__ __forceinline__

constexpr int S_ = 2048;
constexpr int D_ = 512;
constexpr int H_ = 8;
constexpr float SCALE_ = 0.125f;                 // 1/sqrt(64)
constexpr float SCALE_L2E_ = 0.18033688011112f;  // SCALE * log2(e), for exp2-domain scores

using short8 = __attribute__((ext_vector_type(8))) short;
using f32x4  = __attribute__((ext_vector_type(4))) float;

DEVINL unsigned short f2bf(float f){
  unsigned u = __builtin_bit_cast(unsigned, f);
  u += 0x7FFFu + ((u >> 16) & 1u);          // round-to-nearest-even
  return (unsigned short)(u >> 16);
}
DEVINL float bf2f(unsigned short h){
  return __builtin_bit_cast(float, ((unsigned)h) << 16);
}

// Raw v_exp_f32 via the intrinsic (NOT inline asm: the TRANS-op result
// hazard needs compiler-inserted wait states; asm blobs are opaque to the
// hazard recognizer and produced NaNs in R5).
DEVINL float fast_exp2(float x){ return __builtin_amdgcn_exp2f(x); }

DEVINL void gload16(const void* g, void* l){
  __builtin_amdgcn_global_load_lds(
      (__attribute__((address_space(1))) void*)(g),
      (__attribute__((address_space(3))) void*)(l), 16, 0, 0);
}

// ---------------- cast x (f32 -> bf16), 8 elems/thread ----------------
__global__ void cast_x_kernel(const float* __restrict__ x, unsigned short* __restrict__ xb){
  int i = blockIdx.x * 256 + threadIdx.x;
  const float* p = x + (size_t)i * 8;
  float4 a = *(const float4*)p;
  float4 b = *(const float4*)(p + 4);
  short8 o;
  o[0]=f2bf(a.x); o[1]=f2bf(a.y); o[2]=f2bf(a.z); o[3]=f2bf(a.w);
  o[4]=f2bf(b.x); o[5]=f2bf(b.y); o[6]=f2bf(b.z); o[7]=f2bf(b.w);
  *(short8*)(xb + (size_t)i*8) = o;
}

// ---------------- mask (67MB int32) -> bit array (2MB) ----------------
__global__ void mask_bits_kernel(const int* __restrict__ mask, unsigned char* __restrict__ bits){
  unsigned tid = blockIdx.x * 256 + threadIdx.x;   // 2048 blocks -> 524288 threads
  #pragma unroll
  for (int it = 0; it < 4; ++it){
    size_t bidx = (size_t)tid + (size_t)it * 524288;
    const int* p = mask + bidx * 8;
    int4 a = *(const int4*)p;
    int4 c = *(const int4*)(p + 4);
    unsigned v = (unsigned)(a.x != 0)       | ((unsigned)(a.y != 0) << 1)
               | ((unsigned)(a.z != 0) << 2) | ((unsigned)(a.w != 0) << 3)
               | ((unsigned)(c.x != 0) << 4) | ((unsigned)(c.y != 0) << 5)
               | ((unsigned)(c.z != 0) << 6) | ((unsigned)(c.w != 0) << 7);
    bits[bidx] = (unsigned char)v;
  }
}

// ---------------- transpose+cast W [K][N] f32 -> WT [N][K] bf16 -------
// z selects which W (Wq/Wk/Wv/Wo); Wq gets SCALE*log2e folded in.
__global__ void castT_kernel(const float* __restrict__ W0, const float* __restrict__ W1,
                             const float* __restrict__ W2, const float* __restrict__ W3,
                             unsigned short* __restrict__ WT){
  __shared__ float tile[32][33];
  const int z = blockIdx.z;
  const float* W = (z==0) ? W0 : (z==1 ? W1 : (z==2 ? W2 : W3));
  const float scale = (z==0) ? SCALE_L2E_ : 1.0f;
  unsigned short* out = WT + (size_t)z * D_ * D_;
  int n0 = blockIdx.x*32, k0 = blockIdx.y*32;
  int tx = threadIdx.x, ty = threadIdx.y;       // block (32,8)
  #pragma unroll
  for (int j=0;j<4;j++)
    tile[ty+j*8][tx] = W[(size_t)(k0+ty+j*8)*D_ + n0+tx];
  __syncthreads();
  #pragma unroll
  for (int j=0;j<4;j++)
    out[(size_t)(n0+ty+j*8)*D_ + k0+tx] = f2bf(tile[tx][ty+j*8]*scale);
}

// ---------------- GEMM: C[z] = A[z][M,512] @ BT[z][512,512]^T + bias --
// 128x128 tile, BK=64, 4 waves (2x2), mfma 16x16x32 bf16.
// LDS XOR-swizzled via pre-swizzled global_load_lds source (rule #21).
template<typename OutT>
__global__ __launch_bounds__(256) void gemm_bt(
    const unsigned short* __restrict__ A, long long Az,
    const unsigned short* __restrict__ BT, long long Bz,
    const float* __restrict__ bias0, const float* __restrict__ bias1, const float* __restrict__ bias2,
    float bs0, float bs1, float bs2,
    OutT* __restrict__ Cp, long long Cz)
{
  __shared__ unsigned short As[128*64];
  __shared__ unsigned short Bs[128*64];
  const int z = blockIdx.z;
  const unsigned short* Ab = A + (size_t)z*Az;
  const unsigned short* Bb = BT + (size_t)z*Bz;
  const float* bias = (z==0) ? bias0 : (z==1 ? bias1 : bias2);
  const float bscale = (z==0) ? bs0 : (z==1 ? bs1 : bs2);
  OutT* C = Cp + (size_t)z*Cz;
  const int m0 = blockIdx.y*128, n0 = blockIdx.x*128;
  const int t = threadIdx.x, lane = t & 63, w = t >> 6;
  const int wr = w >> 1, wc = w & 1;
  const int g = lane >> 4, lq = lane & 15;
  f32x4 acc[4][4] = {};
  for (int kk = 0; kk < D_; kk += 64){
    #pragma unroll
    for (int p = 0; p < 4; p++){
      int o = p*4096 + t*16;
      int row = o >> 7;                 // LDS row (0..127), 128B/row
      int cb  = o & 127;
      int scb = cb ^ ((row & 7) << 4);  // pre-swizzle the SOURCE
      gload16((const char*)Ab + ((size_t)(m0+row)*D_ + kk)*2 + scb, (char*)As + o);
      gload16((const char*)Bb + ((size_t)(n0+row)*D_ + kk)*2 + scb, (char*)Bs + o);
    }
    __syncthreads();
    #pragma unroll
    for (int ks = 0; ks < 2; ks++){
      short8 af[4], bf[4];
      #pragma unroll
      for (int i = 0; i < 4; i++){
        int rowA = wr*64 + i*16 + lq;
        af[i] = *(const short8*)((const char*)As + ((rowA*128 + ks*64 + g*16) ^ ((rowA&7)<<4)));
        int rowB = wc*64 + i*16 + lq;
        bf[i] = *(const short8*)((const char*)Bs + ((rowB*128 + ks*64 + g*16) ^ ((rowB&7)<<4)));
      }
      #pragma unroll
      for (int i = 0; i < 4; i++)
        #pragma unroll
        for (int j = 0; j < 4; j++)
          acc[i][j] = __builtin_amdgcn_mfma_f32_16x16x32_bf16(af[i], bf[j], acc[i][j], 0, 0, 0);
    }
    __syncthreads();
  }
  #pragma unroll
  for (int i = 0; i < 4; i++){
    #pragma unroll
    for (int j = 0; j < 4; j++){
      int col = n0 + wc*64 + j*16 + lq;
      float bvv = bias[col]*bscale;
      #pragma unroll
      for (int r = 0; r < 4; r++){
        int row = m0 + wr*64 + i*16 + g*4 + r;   // C/D: col=lane&15, row=4g+reg (m89)
        float v = acc[i][j][r] + bvv;
        if constexpr (sizeof(OutT) == 4) C[(size_t)row*D_ + col] = (OutT)v;
        else                             C[(size_t)row*D_ + col] = (OutT)f2bf(v);
      }
    }
  }
}

// ---------------- attention partial Z/M per q-row ---------------------
// Grid (8 qt of 256 rows, 4 kz2, 32 bh); block = 4 waves of the SAME
// (b,h). Each block processes TWO consecutive 256-row K-tiles through
// the same 32KB LDS buffer (restage between, barrier-separated). Q
// fragments stay in registers across both tiles -> Q + mask-bit traffic
// halves vs R9 (147->115 MB L2/L3). Inner loop identical to the proven
// R9 codegen (scalar Z/M; R10's f32x4 accum blew VGPR 56->168).
__global__ __launch_bounds__(256) void attn_zm_kernel(
    const unsigned short* __restrict__ Q, const unsigned short* __restrict__ Kg,
    const unsigned* __restrict__ bitsW, float* __restrict__ Zb, float* __restrict__ Mb)
{
  __shared__ unsigned short Ks[256*64];   // 32KB, swizzled rows of 128B
  const int qt = blockIdx.x, kz2 = blockIdx.y, zz = blockIdx.z;
  const int b = zz >> 3, h = zz & 7;
  const int t = threadIdx.x, lane = t & 63, w = t >> 6;
  const int g = lane >> 4, lq = lane & 15;
  const int qbase = qt*256 + w*64;

  short8 qf[4][2];                        // Q rows in regs (pre-scaled by SCALE*log2e)
  #pragma unroll
  for (int qs = 0; qs < 4; qs++)
    #pragma unroll
    for (int c = 0; c < 2; c++)
      qf[qs][c] = *(const short8*)(Q + ((size_t)(b*S_ + qbase + qs*16 + lq))*D_ + h*64 + c*32 + g*8);

  float Z[4], Mm[4];
  #pragma unroll
  for (int qs = 0; qs < 4; qs++){ Z[qs] = 0.f; Mm[qs] = 0.f; }

  for (int half = 0; half < 2; ++half){
    const int kz = kz2*2 + half;
    if (half) __syncthreads();            // all waves done reading Ks[half-1]

    // stage K-tile: 8 x gload16 per thread, source pre-swizzled (rule #21)
    const char* Kgb = (const char*)Kg + ((size_t)(b*S_ + kz*256))*1024 + h*128;
    #pragma unroll
    for (int p = 0; p < 8; p++){
      int o = p*4096 + t*16;
      int row = o >> 7;                   // 128B per k-row
      int scb = (o & 127) ^ ((row & 7) << 4);
      gload16(Kgb + (size_t)row*1024 + scb, (char*)Ks + o);
    }

    // mask-bit words for this k-tile (latency hides under the stage drain)
    unsigned wb[4][8];
    #pragma unroll
    for (int qs = 0; qs < 4; qs++){
      const uint4* wp = (const uint4*)(bitsW + ((size_t)(b*S_ + qbase + qs*16 + lq))*(S_/32) + kz*8);
      uint4 wA = wp[0], wB = wp[1];
      wb[qs][0]=wA.x; wb[qs][1]=wA.y; wb[qs][2]=wA.z; wb[qs][3]=wA.w;
      wb[qs][4]=wB.x; wb[qs][5]=wB.y; wb[qs][6]=wB.z; wb[qs][7]=wB.w;
    }

    __syncthreads();                      // K-tile staged

    #pragma unroll
    for (int i = 0; i < 16; ++i){         // i covers k rows i*16 .. i*16+15
      const int kt2 = i >> 1, ks = i & 1;
      const int row = i*16 + lq;
      const int sw = (row & 7) << 4;
      short8 A0 = *(const short8*)((const char*)Ks + row*128 + ((g*16) ^ sw));
      short8 A1 = *(const short8*)((const char*)Ks + row*128 + ((64 + g*16) ^ sw));
      #pragma unroll
      for (int qs = 0; qs < 4; qs++){
        f32x4 d = {0.f,0.f,0.f,0.f};
        d = __builtin_amdgcn_mfma_f32_16x16x32_bf16(A0, qf[qs][0], d, 0, 0, 0);
        d = __builtin_amdgcn_mfma_f32_16x16x32_bf16(A1, qf[qs][1], d, 0, 0, 0);
        // d[r]: score(exp2-dom) for kpos = kz*256 + i*16 + 4g + r,
        // q-row = qbase + qs*16 + lq (col=lane&15)
        unsigned nib = wb[qs][kt2] >> (ks*16 + g*4);
        #pragma unroll
        for (int r = 0; r < 4; r++){
          float p = fast_exp2(d[r]);
          Z[qs] += p;
          Mm[qs] = fmaf((float)((nib >> r) & 1u), p, Mm[qs]);
        }
      }
    }
  }
  // merge the 4 k-subsets (lane groups) per q-row; then one atomic per row
  #pragma unroll
  for (int qs = 0; qs < 4; qs++){
    Z[qs]  += __shfl_xor(Z[qs], 16);  Mm[qs] += __shfl_xor(Mm[qs], 16);
    Z[qs]  += __shfl_xor(Z[qs], 32);  Mm[qs] += __shfl_xor(Mm[qs], 32);
  }
  if (g == 0){
    int base = (b*H_ + h)*S_ + qbase + lq;
    #pragma unroll
    for (int qs = 0; qs < 4; qs++){
      atomicAdd(&Zb[base + qs*16], Z[qs]);
      atomicAdd(&Mb[base + qs*16], Mm[qs]);
    }
  }
}

// ---------------- finalize: s[b,h] = sum_q (Z-M)/Z --------------------
__global__ __launch_bounds__(256) void finalize_s(const float* __restrict__ Zb,
                                                  const float* __restrict__ Mb,
                                                  float* __restrict__ sbh){
  const int bh = blockIdx.x;            // 32 blocks
  const int t = threadIdx.x;
  const float* Z = Zb + (size_t)bh*S_;
  const float* M = Mb + (size_t)bh*S_;
  float acc = 0.f;
  #pragma unroll
  for (int q = t; q < S_; q += 256){
    float z = Z[q];
    acc += (z - M[q]) / z;
  }
  #pragma unroll
  for (int m = 1; m < 64; m <<= 1) acc += __shfl_xor(acc, m);
  __shared__ float wsum[4];
  if ((t & 63) == 0) wsum[t >> 6] = acc;
  __syncthreads();
  if (t == 0) sbh[bh] = wsum[0] + wsum[1] + wsum[2] + wsum[3];
}

// ---------------- fold s into Wo columns: WoST[b][n][k] = WoT[n][k]*s[b,k/64]
__global__ void scale_woT_kernel(const unsigned short* __restrict__ WoT,
                                 const float* __restrict__ sbh,
                                 unsigned short* __restrict__ outw){
  int i = blockIdx.x*256 + threadIdx.x;   // 131072 threads, 8 elems each
  size_t e = (size_t)i * 8;
  int k = (int)(e & 511);
  int n = (int)((e >> 9) & 511);
  int b = (int)(e >> 18);
  float sv = sbh[b*H_ + (k >> 6)];
  short8 wv = *(const short8*)(WoT + (size_t)n*D_ + k);
  short8 o;
  #pragma unroll
  for (int j = 0; j < 8; j++) o[j] = (short)f2bf(bf2f((unsigned short)wv[j]) * sv);
  *(short8*)(outw + e) = o;
}

extern "C" void kernel_launch(void* const* d_in, const int* in_sizes, int n_in,
                              void* d_out, int out_size, void* d_ws, size_t ws_size,
                              hipStream_t stream) {
  (void)in_sizes; (void)n_in; (void)out_size; (void)ws_size;
  const float* x  = (const float*)d_in[0];
  const int* mask = (const int*)d_in[1];
  const float* Wq = (const float*)d_in[2];
  const float* bq = (const float*)d_in[3];
  const float* Wk = (const float*)d_in[4];
  const float* bk = (const float*)d_in[5];
  const float* Wv = (const float*)d_in[6];
  const float* bv = (const float*)d_in[7];
  const float* Wo = (const float*)d_in[8];
  const float* bo = (const float*)d_in[9];
  float* out = (float*)d_out;

  char* ws = (char*)d_ws;
  unsigned short* xb   = (unsigned short*)(ws);             // 8 MB, dead after QKV gemm
  unsigned short* wT   = (unsigned short*)(ws +  8388608);  // WqT,WkT,WvT,WoT (4x512 KB)
  unsigned short* woT  = (unsigned short*)(ws +  9961472);  //   (= wT + 3*262144)
  unsigned short* Qb   = (unsigned short*)(ws + 10485760);
  unsigned short* Kb   = (unsigned short*)(ws + 18874368);
  unsigned short* Vb   = (unsigned short*)(ws + 27262976);
  unsigned short* woST = (unsigned short*)(ws + 35651584);  // 4x512 KB
  float*          sbh  = (float*)         (ws + 37748736);  // 32 floats
  // Z/M partials overlap the (dead-by-then) xb region: 2 x 256 KB
  float*          Zbuf = (float*)(ws);
  float*          Mbuf = (float*)(ws + 262144);
  // mask bit array (2MB) overlaps woST: bits die before scale_woT writes it
  unsigned char*  bits = (unsigned char*)(ws + 35651584);

  cast_x_kernel<<<2048, 256, 0, stream>>>(x, xb);
  castT_kernel<<<dim3(16,16,4), dim3(32,8), 0, stream>>>(Wq, Wk, Wv, Wo, wT);
  mask_bits_kernel<<<2048, 256, 0, stream>>>(mask, bits);

  // QKV projections: z=0..2 -> Q,K,V (bias for Q scaled by SCALE*log2e too)
  gemm_bt<unsigned short><<<dim3(4,64,3), 256, 0, stream>>>(
      xb, 0LL, wT, 262144LL, bq, bk, bv, SCALE_L2E_, 1.0f, 1.0f, Qb, 4194304LL);

  // xb is dead now; reuse its space for Z/M partial sums
  hipMemsetAsync(Zbuf, 0, 524288, stream);

  attn_zm_kernel<<<dim3(8,4,32), 256, 0, stream>>>(Qb, Kb, (const unsigned*)bits, Zbuf, Mbuf);
  finalize_s<<<32, 256, 0, stream>>>(Zbuf, Mbuf, sbh);

  scale_woT_kernel<<<512, 256, 0, stream>>>(woT, sbh, woST);

  // out[b] = V[b] @ WoST[b]^T + bo  (fp32 out)
  gemm_bt<float><<<dim3(4,16,4), 256, 0, stream>>>(
      Vb, 1048576LL, woST, 262144LL, bo, bo, bo, 1.0f, 1.0f, 1.0f, out, 1048576LL);
}

// Round 12
// 108.637 us; speedup vs baseline: 1.3263x; 1.1841x over previous
//
#include <hip/hip_runtime.h>
#include <cstdint>
#include <cstddef>

#define DEVINL __device__ __forceinline__

constexpr int S_ = 2048;
constexpr int D_ = 512;
constexpr int H_ = 8;
constexpr float SCALE_ = 0.125f;                 // 1/sqrt(64)
constexpr float SCALE_L2E_ = 0.18033688011112f;  // SCALE * log2(e), for exp2-domain scores

using short8 = __attribute__((ext_vector_type(8))) short;
using f32x4  = __attribute__((ext_vector_type(4))) float;

DEVINL unsigned short f2bf(float f){
  unsigned u = __builtin_bit_cast(unsigned, f);
  u += 0x7FFFu + ((u >> 16) & 1u);          // round-to-nearest-even
  return (unsigned short)(u >> 16);
}
DEVINL float bf2f(unsigned short h){
  return __builtin_bit_cast(float, ((unsigned)h) << 16);
}

// Raw v_exp_f32 via the intrinsic (NOT inline asm: the TRANS-op result
// hazard needs compiler-inserted wait states; asm blobs are opaque to the
// hazard recognizer and produced NaNs in R5).
DEVINL float fast_exp2(float x){ return __builtin_amdgcn_exp2f(x); }

DEVINL void gload16(const void* g, void* l){
  __builtin_amdgcn_global_load_lds(
      (__attribute__((address_space(1))) void*)(g),
      (__attribute__((address_space(3))) void*)(l), 16, 0, 0);
}

// ---------------- cast x (f32 -> bf16), 8 elems/thread ----------------
__global__ void cast_x_kernel(const float* __restrict__ x, unsigned short* __restrict__ xb){
  int i = blockIdx.x * 256 + threadIdx.x;
  const float* p = x + (size_t)i * 8;
  float4 a = *(const float4*)p;
  float4 b = *(const float4*)(p + 4);
  short8 o;
  o[0]=f2bf(a.x); o[1]=f2bf(a.y); o[2]=f2bf(a.z); o[3]=f2bf(a.w);
  o[4]=f2bf(b.x); o[5]=f2bf(b.y); o[6]=f2bf(b.z); o[7]=f2bf(b.w);
  *(short8*)(xb + (size_t)i*8) = o;
}

// ---------------- mask (67MB int32) -> bit array (2MB) ----------------
__global__ void mask_bits_kernel(const int* __restrict__ mask, unsigned char* __restrict__ bits){
  unsigned tid = blockIdx.x * 256 + threadIdx.x;   // 2048 blocks -> 524288 threads
  #pragma unroll
  for (int it = 0; it < 4; ++it){
    size_t bidx = (size_t)tid + (size_t)it * 524288;
    const int* p = mask + bidx * 8;
    int4 a = *(const int4*)p;
    int4 c = *(const int4*)(p + 4);
    unsigned v = (unsigned)(a.x != 0)       | ((unsigned)(a.y != 0) << 1)
               | ((unsigned)(a.z != 0) << 2) | ((unsigned)(a.w != 0) << 3)
               | ((unsigned)(c.x != 0) << 4) | ((unsigned)(c.y != 0) << 5)
               | ((unsigned)(c.z != 0) << 6) | ((unsigned)(c.w != 0) << 7);
    bits[bidx] = (unsigned char)v;
  }
}

// ---------------- transpose+cast W [K][N] f32 -> WT [N][K] bf16 -------
// z selects which W (Wq/Wk/Wv/Wo); Wq gets SCALE*log2e folded in.
__global__ void castT_kernel(const float* __restrict__ W0, const float* __restrict__ W1,
                             const float* __restrict__ W2, const float* __restrict__ W3,
                             unsigned short* __restrict__ WT){
  __shared__ float tile[32][33];
  const int z = blockIdx.z;
  const float* W = (z==0) ? W0 : (z==1 ? W1 : (z==2 ? W2 : W3));
  const float scale = (z==0) ? SCALE_L2E_ : 1.0f;
  unsigned short* out = WT + (size_t)z * D_ * D_;
  int n0 = blockIdx.x*32, k0 = blockIdx.y*32;
  int tx = threadIdx.x, ty = threadIdx.y;       // block (32,8)
  #pragma unroll
  for (int j=0;j<4;j++)
    tile[ty+j*8][tx] = W[(size_t)(k0+ty+j*8)*D_ + n0+tx];
  __syncthreads();
  #pragma unroll
  for (int j=0;j<4;j++)
    out[(size_t)(n0+ty+j*8)*D_ + k0+tx] = f2bf(tile[tx][ty+j*8]*scale);
}

// ---------------- GEMM: C[z] = A[z][M,512] @ BT[z][512,512]^T + bias --
// 128x128 tile, BK=64, 4 waves (2x2), mfma 16x16x32 bf16.
// LDS XOR-swizzled via pre-swizzled global_load_lds source (rule #21).
template<typename OutT>
__global__ __launch_bounds__(256) void gemm_bt(
    const unsigned short* __restrict__ A, long long Az,
    const unsigned short* __restrict__ BT, long long Bz,
    const float* __restrict__ bias0, const float* __restrict__ bias1, const float* __restrict__ bias2,
    float bs0, float bs1, float bs2,
    OutT* __restrict__ Cp, long long Cz)
{
  __shared__ unsigned short As[128*64];
  __shared__ unsigned short Bs[128*64];
  const int z = blockIdx.z;
  const unsigned short* Ab = A + (size_t)z*Az;
  const unsigned short* Bb = BT + (size_t)z*Bz;
  const float* bias = (z==0) ? bias0 : (z==1 ? bias1 : bias2);
  const float bscale = (z==0) ? bs0 : (z==1 ? bs1 : bs2);
  OutT* C = Cp + (size_t)z*Cz;
  const int m0 = blockIdx.y*128, n0 = blockIdx.x*128;
  const int t = threadIdx.x, lane = t & 63, w = t >> 6;
  const int wr = w >> 1, wc = w & 1;
  const int g = lane >> 4, lq = lane & 15;
  f32x4 acc[4][4] = {};
  for (int kk = 0; kk < D_; kk += 64){
    #pragma unroll
    for (int p = 0; p < 4; p++){
      int o = p*4096 + t*16;
      int row = o >> 7;                 // LDS row (0..127), 128B/row
      int cb  = o & 127;
      int scb = cb ^ ((row & 7) << 4);  // pre-swizzle the SOURCE
      gload16((const char*)Ab + ((size_t)(m0+row)*D_ + kk)*2 + scb, (char*)As + o);
      gload16((const char*)Bb + ((size_t)(n0+row)*D_ + kk)*2 + scb, (char*)Bs + o);
    }
    __syncthreads();
    #pragma unroll
    for (int ks = 0; ks < 2; ks++){
      short8 af[4], bf[4];
      #pragma unroll
      for (int i = 0; i < 4; i++){
        int rowA = wr*64 + i*16 + lq;
        af[i] = *(const short8*)((const char*)As + ((rowA*128 + ks*64 + g*16) ^ ((rowA&7)<<4)));
        int rowB = wc*64 + i*16 + lq;
        bf[i] = *(const short8*)((const char*)Bs + ((rowB*128 + ks*64 + g*16) ^ ((rowB&7)<<4)));
      }
      #pragma unroll
      for (int i = 0; i < 4; i++)
        #pragma unroll
        for (int j = 0; j < 4; j++)
          acc[i][j] = __builtin_amdgcn_mfma_f32_16x16x32_bf16(af[i], bf[j], acc[i][j], 0, 0, 0);
    }
    __syncthreads();
  }
  #pragma unroll
  for (int i = 0; i < 4; i++){
    #pragma unroll
    for (int j = 0; j < 4; j++){
      int col = n0 + wc*64 + j*16 + lq;
      float bvv = bias[col]*bscale;
      #pragma unroll
      for (int r = 0; r < 4; r++){
        int row = m0 + wr*64 + i*16 + g*4 + r;   // C/D: col=lane&15, row=4g+reg (m89)
        float v = acc[i][j][r] + bvv;
        if constexpr (sizeof(OutT) == 4) C[(size_t)row*D_ + col] = (OutT)v;
        else                             C[(size_t)row*D_ + col] = (OutT)f2bf(v);
      }
    }
  }
}

// ---------------- attention partial Z/M per q-row ---------------------
// Grid (4 qt of 512 rows, 8 kz, 32 bh); block = 8 waves of the SAME
// (b,h), wave w owns q-rows qt*512+w*64..+64. 1024 blocks = exactly
// 4 blocks/CU, all co-resident (32 waves/CU) -> stages overlap compute
// across blocks. K staged once per block (32 MB total K traffic, half
// of R9); body is byte-identical to the proven R9 codegen (VGPR 56).
__global__ __launch_bounds__(512) void attn_zm_kernel(
    const unsigned short* __restrict__ Q, const unsigned short* __restrict__ Kg,
    const unsigned* __restrict__ bitsW, float* __restrict__ Zb, float* __restrict__ Mb)
{
  __shared__ unsigned short Ks[256*64];   // 32KB, swizzled rows of 128B
  const int qt = blockIdx.x, kz = blockIdx.y, zz = blockIdx.z;
  const int b = zz >> 3, h = zz & 7;
  const int t = threadIdx.x, lane = t & 63, w = t >> 6;
  const int g = lane >> 4, lq = lane & 15;
  const int qbase = qt*512 + w*64;

  // stage K-tile: 4 x gload16 per thread (512 threads), pre-swizzled src
  const char* Kgb = (const char*)Kg + ((size_t)(b*S_ + kz*256))*1024 + h*128;
  #pragma unroll
  for (int p = 0; p < 4; p++){
    int o = p*8192 + t*16;
    int row = o >> 7;                   // 128B per k-row
    int scb = (o & 127) ^ ((row & 7) << 4);
    gload16(Kgb + (size_t)row*1024 + scb, (char*)Ks + o);
  }

  // mask-bit words: 4 q-rows x 8 k-tiles, preloaded (static idx)
  unsigned wb[4][8];
  #pragma unroll
  for (int qs = 0; qs < 4; qs++){
    const uint4* wp = (const uint4*)(bitsW + ((size_t)(b*S_ + qbase + qs*16 + lq))*(S_/32) + kz*8);
    uint4 wA = wp[0], wB = wp[1];
    wb[qs][0]=wA.x; wb[qs][1]=wA.y; wb[qs][2]=wA.z; wb[qs][3]=wA.w;
    wb[qs][4]=wB.x; wb[qs][5]=wB.y; wb[qs][6]=wB.z; wb[qs][7]=wB.w;
  }

  short8 qf[4][2];                        // Q rows in regs (pre-scaled by SCALE*log2e)
  #pragma unroll
  for (int qs = 0; qs < 4; qs++)
    #pragma unroll
    for (int c = 0; c < 2; c++)
      qf[qs][c] = *(const short8*)(Q + ((size_t)(b*S_ + qbase + qs*16 + lq))*D_ + h*64 + c*32 + g*8);

  float Z[4], Mm[4];
  #pragma unroll
  for (int qs = 0; qs < 4; qs++){ Z[qs] = 0.f; Mm[qs] = 0.f; }

  __syncthreads();                        // K-tile ready (the only barrier)

  #pragma unroll
  for (int i = 0; i < 16; ++i){           // i covers k rows i*16 .. i*16+15
    const int kt2 = i >> 1, ks = i & 1;
    const int row = i*16 + lq;
    const int sw = (row & 7) << 4;
    short8 A0 = *(const short8*)((const char*)Ks + row*128 + ((g*16) ^ sw));
    short8 A1 = *(const short8*)((const char*)Ks + row*128 + ((64 + g*16) ^ sw));
    #pragma unroll
    for (int qs = 0; qs < 4; qs++){
      f32x4 d = {0.f,0.f,0.f,0.f};
      d = __builtin_amdgcn_mfma_f32_16x16x32_bf16(A0, qf[qs][0], d, 0, 0, 0);
      d = __builtin_amdgcn_mfma_f32_16x16x32_bf16(A1, qf[qs][1], d, 0, 0, 0);
      // d[r]: score(exp2-dom) for kpos = kz*256 + i*16 + 4g + r,
      // q-row = qbase + qs*16 + lq (col=lane&15)
      unsigned nib = wb[qs][kt2] >> (ks*16 + g*4);
      #pragma unroll
      for (int r = 0; r < 4; r++){
        float p = fast_exp2(d[r]);
        Z[qs] += p;
        Mm[qs] = fmaf((float)((nib >> r) & 1u), p, Mm[qs]);
      }
    }
  }
  // merge the 4 k-subsets (lane groups) per q-row; then one atomic per row
  #pragma unroll
  for (int qs = 0; qs < 4; qs++){
    Z[qs]  += __shfl_xor(Z[qs], 16);  Mm[qs] += __shfl_xor(Mm[qs], 16);
    Z[qs]  += __shfl_xor(Z[qs], 32);  Mm[qs] += __shfl_xor(Mm[qs], 32);
  }
  if (g == 0){
    int base = (b*H_ + h)*S_ + qbase + lq;
    #pragma unroll
    for (int qs = 0; qs < 4; qs++){
      atomicAdd(&Zb[base + qs*16], Z[qs]);
      atomicAdd(&Mb[base + qs*16], Mm[qs]);
    }
  }
}

// ---------------- finalize: s[b,h] = sum_q (Z-M)/Z --------------------
__global__ __launch_bounds__(256) void finalize_s(const float* __restrict__ Zb,
                                                  const float* __restrict__ Mb,
                                                  float* __restrict__ sbh){
  const int bh = blockIdx.x;            // 32 blocks
  const int t = threadIdx.x;
  const float* Z = Zb + (size_t)bh*S_;
  const float* M = Mb + (size_t)bh*S_;
  float acc = 0.f;
  #pragma unroll
  for (int q = t; q < S_; q += 256){
    float z = Z[q];
    acc += (z - M[q]) / z;
  }
  #pragma unroll
  for (int m = 1; m < 64; m <<= 1) acc += __shfl_xor(acc, m);
  __shared__ float wsum[4];
  if ((t & 63) == 0) wsum[t >> 6] = acc;
  __syncthreads();
  if (t == 0) sbh[bh] = wsum[0] + wsum[1] + wsum[2] + wsum[3];
}

// ---------------- fold s into Wo columns: WoST[b][n][k] = WoT[n][k]*s[b,k/64]
__global__ void scale_woT_kernel(const unsigned short* __restrict__ WoT,
                                 const float* __restrict__ sbh,
                                 unsigned short* __restrict__ outw){
  int i = blockIdx.x*256 + threadIdx.x;   // 131072 threads, 8 elems each
  size_t e = (size_t)i * 8;
  int k = (int)(e & 511);
  int n = (int)((e >> 9) & 511);
  int b = (int)(e >> 18);
  float sv = sbh[b*H_ + (k >> 6)];
  short8 wv = *(const short8*)(WoT + (size_t)n*D_ + k);
  short8 o;
  #pragma unroll
  for (int j = 0; j < 8; j++) o[j] = (short)f2bf(bf2f((unsigned short)wv[j]) * sv);
  *(short8*)(outw + e) = o;
}

extern "C" void kernel_launch(void* const* d_in, const int* in_sizes, int n_in,
                              void* d_out, int out_size, void* d_ws, size_t ws_size,
                              hipStream_t stream) {
  (void)in_sizes; (void)n_in; (void)out_size; (void)ws_size;
  const float* x  = (const float*)d_in[0];
  const int* mask = (const int*)d_in[1];
  const float* Wq = (const float*)d_in[2];
  const float* bq = (const float*)d_in[3];
  const float* Wk = (const float*)d_in[4];
  const float* bk = (const float*)d_in[5];
  const float* Wv = (const float*)d_in[6];
  const float* bv = (const float*)d_in[7];
  const float* Wo = (const float*)d_in[8];
  const float* bo = (const float*)d_in[9];
  float* out = (float*)d_out;

  char* ws = (char*)d_ws;
  unsigned short* xb   = (unsigned short*)(ws);             // 8 MB, dead after QKV gemm
  unsigned short* wT   = (unsigned short*)(ws +  8388608);  // WqT,WkT,WvT,WoT (4x512 KB)
  unsigned short* woT  = (unsigned short*)(ws +  9961472);  //   (= wT + 3*262144)
  unsigned short* Qb   = (unsigned short*)(ws + 10485760);
  unsigned short* Kb   = (unsigned short*)(ws + 18874368);
  unsigned short* Vb   = (unsigned short*)(ws + 27262976);
  unsigned short* woST = (unsigned short*)(ws + 35651584);  // 4x512 KB
  float*          sbh  = (float*)         (ws + 37748736);  // 32 floats
  // Z/M partials overlap the (dead-by-then) xb region: 2 x 256 KB
  float*          Zbuf = (float*)(ws);
  float*          Mbuf = (float*)(ws + 262144);
  // mask bit array (2MB) overlaps woST: bits die before scale_woT writes it
  unsigned char*  bits = (unsigned char*)(ws + 35651584);

  cast_x_kernel<<<2048, 256, 0, stream>>>(x, xb);
  castT_kernel<<<dim3(16,16,4), dim3(32,8), 0, stream>>>(Wq, Wk, Wv, Wo, wT);
  mask_bits_kernel<<<2048, 256, 0, stream>>>(mask, bits);

  // QKV projections: z=0..2 -> Q,K,V (bias for Q scaled by SCALE*log2e too)
  gemm_bt<unsigned short><<<dim3(4,64,3), 256, 0, stream>>>(
      xb, 0LL, wT, 262144LL, bq, bk, bv, SCALE_L2E_, 1.0f, 1.0f, Qb, 4194304LL);

  // xb is dead now; reuse its space for Z/M partial sums
  hipMemsetAsync(Zbuf, 0, 524288, stream);

  attn_zm_kernel<<<dim3(4,8,32), 512, 0, stream>>>(Qb, Kb, (const unsigned*)bits, Zbuf, Mbuf);
  finalize_s<<<32, 256, 0, stream>>>(Zbuf, Mbuf, sbh);

  scale_woT_kernel<<<512, 256, 0, stream>>>(woT, sbh, woST);

  // out[b] = V[b] @ WoST[b]^T + bo  (fp32 out)
  gemm_bt<float><<<dim3(4,16,4), 256, 0, stream>>>(
      Vb, 1048576LL, woST, 262144LL, bo, bo, bo, 1.0f, 1.0f, 1.0f, out, 1048576LL);
}